// Round 6
// baseline (290.832 us; speedup 1.0000x reference)
//
#include <hip/hip_runtime.h>
#include <hip/hip_cooperative_groups.h>

namespace cg = cooperative_groups;

#define H_IN   181
#define W_IN   360
#define NLAT   361
#define NLON   720
#define CIN    16
#define COUT   16
#define KSZ    3
#define NNZ    8192
#define HW     (H_IN * W_IN)          // 65160
#define KHW    (KSZ * HW)             // 195480 ushort4-elems per channel-quad slice
#define MAXB   48                     // per (ho,parity) capacity (mean 11.3)
#define NUNIT  (NLAT * 8)             // 2888 gather units (ho, q, half)
#define XW_BYTES ((size_t)4 * KHW * 8)  // 6,255,360 B bf16 quad-packed

// Round 6: single cooperative kernel. r4/r5 showed two very different K1/K2
// implementations both land at ~29-30us while the work model says ~12 ->
// the residual is structural (per-dispatch overhead and/or cross-XCD xw
// latency), not instructions. This round removes one dispatch + the
// inter-kernel drain entirely: mix + bucket -> threadfence + grid.sync()
// -> gather, in one launch. Grid is sized from an occupancy query (capped
// 1024x256, co-resident by construction); if cooperative launch is refused
// the same kernel runs twice as a phase-split pair (phase=1 then phase=2).

static __device__ __forceinline__ unsigned short f2bf(float f) {
    unsigned int u = __float_as_uint(f);
    u = (u + 0x7fffu + ((u >> 16) & 1u)) >> 16;
    return (unsigned short)u;
}
static __device__ __forceinline__ void bf2_to_f2(unsigned int d, float& lo, float& hi) {
    lo = __uint_as_float(d << 16);
    hi = __uint_as_float(d & 0xffff0000u);
}
static __device__ __forceinline__ int rfl_i(int i) {
    return __builtin_amdgcn_readfirstlane(i);
}
static __device__ __forceinline__ float rfl_f(float f) {
    return __uint_as_float(__builtin_amdgcn_readfirstlane(__float_as_uint(f)));
}
__device__ __forceinline__ void fma4(float4& a, float v, const float4& f) {
    a.x += v * f.x; a.y += v * f.y; a.z += v * f.z; a.w += v * f.w;
}
static __device__ __forceinline__ float4 ld_bf4(const ushort4* p) {
    const uint2 d = *(const uint2*)p;
    float4 f;
    bf2_to_f2(d.x, f.x, f.y);
    bf2_to_f2(d.y, f.z, f.w);
    return f;
}

// phase: 0 = everything with grid.sync (cooperative launch)
//        1 = mix + bucket only      2 = gather only   (fallback pair)
__global__ __launch_bounds__(256, 2) void disco_fused(
    const float* __restrict__ x,        // [CIN][H_IN][W_IN]
    const float* __restrict__ w,        // [COUT][CIN][KSZ]
    const float* __restrict__ bias,     // [COUT]
    const int*   __restrict__ ker_idx,
    const int*   __restrict__ row_idx,
    const int*   __restrict__ col_idx,
    const float* __restrict__ vals,
    ushort4*     __restrict__ xw4,      // [4][KSZ*H*W] bf16 quads
    int*         __restrict__ gcnt,     // [NLAT][2] padded counts
    int4*        __restrict__ gseg,     // [NLAT][2][MAXB] {base, ps, valbits, 0}
    float*       __restrict__ out,      // [COUT][NLAT][NLON]
    int phase)
{
    const int tid = threadIdx.x;
    const int bid = blockIdx.x;
    const int nb  = gridDim.x;

    __shared__ float swk[KSZ * CIN * COUT];   // [k][c][co]
    __shared__ int   s_cnt[2];
    __shared__ int   s_b [2 * MAXB];
    __shared__ int   s_ps[2 * MAXB];
    __shared__ float s_v [2 * MAXB];

    if (phase <= 1) {
        // ---- stage weights as [k][c][co] for broadcast float4 reads ----
        for (int i = tid; i < KSZ * CIN * COUT; i += 256) {
            const int k = i >> 8, rem = i & 255;
            const int c = rem >> 4, co = rem & 15;
            swk[i] = w[(co * CIN + c) * KSZ + k];
        }
        __syncthreads();

        // ---- mix: grid-stride over KHW elems, all 4 quads per thread ----
        for (int idx = bid * 256 + tid; idx < KHW; idx += nb * 256) {
            const int k   = idx / HW;
            const int pos = idx - k * HW;
            float4 a0 = make_float4(0.f, 0.f, 0.f, 0.f), a1 = a0, a2 = a0, a3 = a0;
#pragma unroll
            for (int c = 0; c < CIN; ++c) {
                const float xv = x[c * HW + pos];
                const float4* wr = (const float4*)(swk + (k * CIN + c) * COUT);
                fma4(a0, xv, wr[0]); fma4(a1, xv, wr[1]);
                fma4(a2, xv, wr[2]); fma4(a3, xv, wr[3]);
            }
            ushort4 b;
            b.x = f2bf(a0.x); b.y = f2bf(a0.y); b.z = f2bf(a0.z); b.w = f2bf(a0.w);
            xw4[0 * KHW + idx] = b;
            b.x = f2bf(a1.x); b.y = f2bf(a1.y); b.z = f2bf(a1.z); b.w = f2bf(a1.w);
            xw4[1 * KHW + idx] = b;
            b.x = f2bf(a2.x); b.y = f2bf(a2.y); b.z = f2bf(a2.z); b.w = f2bf(a2.w);
            xw4[2 * KHW + idx] = b;
            b.x = f2bf(a3.x); b.y = f2bf(a3.y); b.z = f2bf(a3.z); b.w = f2bf(a3.w);
            xw4[3 * KHW + idx] = b;
        }

        // ---- bucket build: block-stride over latitudes ----
        for (int ho = bid; ho < NLAT; ho += nb) {
            if (tid < 2) s_cnt[tid] = 0;
            for (int i = tid; i < 2 * MAXB; i += 256) {
                s_b[i] = 0; s_ps[i] = 0; s_v[i] = 0.f;
            }
            __syncthreads();

            const int cbase = ho * NLON;
            const int4* __restrict__ col4 = (const int4*)col_idx;
            for (int n4 = tid; n4 < NNZ / 4; n4 += 256) {
                const int4 c4 = col4[n4];
#pragma unroll
                for (int j = 0; j < 4; ++j) {
                    const int c = (j == 0) ? c4.x : (j == 1) ? c4.y : (j == 2) ? c4.z : c4.w;
                    const unsigned d = (unsigned)(c - cbase);   // <720 iff lat==ho
                    if (d < (unsigned)NLON) {
                        const int n    = 4 * n4 + j;
                        const int pe   = (int)(d & 1u);
                        const int slot = atomicAdd(&s_cnt[pe], 1);
                        if (slot < MAXB) {
                            s_b [pe * MAXB + slot] = (ker_idx[n] * H_IN + row_idx[n]) * W_IN;
                            s_ps[pe * MAXB + slot] = (int)(d >> 1);
                            s_v [pe * MAXB + slot] = vals[n];
                        }
                    }
                }
            }
            __syncthreads();
            if (tid < 2) {
                int c = s_cnt[tid] < MAXB ? s_cnt[tid] : MAXB;
                gcnt[ho * 2 + tid] = (c + 3) & ~3;   // x4-padded; pads are zero
            }
            for (int i = tid; i < 2 * MAXB; i += 256)
                gseg[ho * 2 * MAXB + i] =
                    make_int4(s_b[i], s_ps[i], __float_as_int(s_v[i]), 0);
            __syncthreads();   // protect LDS reuse on next ho iteration
        }
    }

    if (phase == 0) {
        __threadfence();
        cg::this_grid().sync();
    }

    if (phase != 1) {
        // ---- gather: grid-stride over 2888 (ho, q, half) units ----
        for (int u = bid; u < NUNIT; u += nb) {
            const int ho   = u >> 3;
            const int q    = (u >> 1) & 3;
            const int half = u & 1;

            const int2 cnt2 = ((const int2*)gcnt)[ho];
            const int cntE = rfl_i(cnt2.x);
            const int cntO = rfl_i(cnt2.y);

            if (tid < 180) {
                const int lonIdx = half * 180 + tid;    // lon>>1 in [0,360)
                const float4 bq = ((const float4*)bias)[q];
                float4 accE = bq, accO = bq;
                const ushort4* __restrict__ slice = xw4 + (size_t)q * KHW;
                const int4*   __restrict__ seg    = gseg + ho * 2 * MAXB;

#define SEG(PE, CNT, ACC)                                                       \
    for (int e = 0; e < (CNT); e += 4) {                                        \
        const int4 s0 = seg[(PE) * MAXB + e + 0];                               \
        const int4 s1 = seg[(PE) * MAXB + e + 1];                               \
        const int4 s2 = seg[(PE) * MAXB + e + 2];                               \
        const int4 s3 = seg[(PE) * MAXB + e + 3];                               \
        const int   b0 = rfl_i(s0.x), b1 = rfl_i(s1.x);                         \
        const int   b2 = rfl_i(s2.x), b3 = rfl_i(s3.x);                         \
        const int   p0 = rfl_i(s0.y), p1 = rfl_i(s1.y);                         \
        const int   p2 = rfl_i(s2.y), p3 = rfl_i(s3.y);                         \
        const float v0 = rfl_f(__int_as_float(s0.z));                           \
        const float v1 = rfl_f(__int_as_float(s1.z));                           \
        const float v2 = rfl_f(__int_as_float(s2.z));                           \
        const float v3 = rfl_f(__int_as_float(s3.z));                           \
        int y0 = lonIdx - p0; y0 += (y0 >> 31) & 360;                           \
        int y1 = lonIdx - p1; y1 += (y1 >> 31) & 360;                           \
        int y2 = lonIdx - p2; y2 += (y2 >> 31) & 360;                           \
        int y3 = lonIdx - p3; y3 += (y3 >> 31) & 360;                           \
        const float4 f0 = ld_bf4(slice + b0 + y0);                              \
        const float4 f1 = ld_bf4(slice + b1 + y1);                              \
        const float4 f2 = ld_bf4(slice + b2 + y2);                              \
        const float4 f3 = ld_bf4(slice + b3 + y3);                              \
        fma4(ACC, v0, f0); fma4(ACC, v1, f1);                                   \
        fma4(ACC, v2, f2); fma4(ACC, v3, f3);                                   \
    }
                SEG(0, cntE, accE)
                SEG(1, cntO, accO)
#undef SEG

                const float2 rr[4] = {
                    make_float2(accE.x, accO.x), make_float2(accE.y, accO.y),
                    make_float2(accE.z, accO.z), make_float2(accE.w, accO.w) };
#pragma unroll
                for (int j = 0; j < 4; ++j) {
                    const int co = 4 * q + j;
                    *(float2*)(out + ((size_t)co * NLAT + ho) * NLON + 2 * lonIdx) = rr[j];
                }
            }
        }
    }
}

// ---------------------------------------------------------------------------
extern "C" void kernel_launch(void* const* d_in, const int* in_sizes, int n_in,
                              void* d_out, int out_size, void* d_ws, size_t ws_size,
                              hipStream_t stream) {
    const float* x       = (const float*)d_in[0];
    const float* weight  = (const float*)d_in[1];
    const float* bias    = (const float*)d_in[2];
    const int*   ker_idx = (const int*)d_in[3];
    const int*   row_idx = (const int*)d_in[4];
    const int*   col_idx = (const int*)d_in[5];
    const float* vals    = (const float*)d_in[6];
    float* out = (float*)d_out;

    // workspace layout (poison fill is unconditional -> ws use is free)
    ushort4* xw4  = (ushort4*)d_ws;                           // 6,255,360 B
    int*     gcnt = (int*)((char*)d_ws + XW_BYTES);           // [NLAT*2]
    int4*    gseg = (int4*)((char*)d_ws + XW_BYTES + 4096);   // [NLAT*2*MAXB]

    // size cooperative grid from occupancy (once); cap 1024 = 4 blk/CU
    static int coop_grid = -2;
    if (coop_grid == -2) {
        int occ = 0;
        if (hipOccupancyMaxActiveBlocksPerMultiprocessor(&occ, disco_fused, 256, 0)
                == hipSuccess && occ > 0) {
            long g = (long)occ * 256;
            coop_grid = (int)(g > 1024 ? 1024 : g);
        } else {
            coop_grid = -1;
        }
    }

    if (coop_grid > 0) {
        int phase = 0;
        void* args[] = {
            (void*)&x, (void*)&weight, (void*)&bias,
            (void*)&ker_idx, (void*)&row_idx, (void*)&col_idx, (void*)&vals,
            (void*)&xw4, (void*)&gcnt, (void*)&gseg, (void*)&out, (void*)&phase };
        hipError_t e = hipLaunchCooperativeKernel(
            disco_fused, dim3(coop_grid), dim3(256), args, 0, stream);
        if (e == hipSuccess) return;
        coop_grid = -1;   // cooperative refused (e.g. capture) -> pair fallback
    }

    disco_fused<<<1024, 256, 0, stream>>>(
        x, weight, bias, ker_idx, row_idx, col_idx, vals,
        xw4, gcnt, gseg, out, 1);
    disco_fused<<<1444, 256, 0, stream>>>(
        x, weight, bias, ker_idx, row_idx, col_idx, vals,
        xw4, gcnt, gseg, out, 2);
}

// Round 7
// 93.139 us; speedup vs baseline: 3.1226x; 3.1226x over previous
//
#include <hip/hip_runtime.h>

#define H_IN   181
#define W_IN   360
#define NLAT   361
#define NLON   720
#define CIN    16
#define COUT   16
#define KSZ    3
#define NNZ    8192
#define HW     (H_IN * W_IN)               // 65160
#define KHW    (KSZ * HW)                  // 195480 ushort8-elems per half-slice
#define MAXB   48                          // per (ho,parity) capacity (mean 11.3)
#define NMIX_BLK 768                       // 3 k-planes x 256 chunks (k = bid>>8)
#define XW_BYTES ((size_t)2 * KHW * 16)    // 6,255,360 B bf16 8ch-packed

// Round 7: r4's two-dispatch structure (best measured, 93.6us) with three
// safe micro-fixes. r6 proved cooperative grid.sync costs ~250us on gfx950
// (device-scope spin across 8 non-coherent XCDs) -> two dispatches it is.
//  - K1 mix: block-uniform k (no per-thread divide), weights staged [k][c][co]
//    and read as broadcast ds_read_b128; output stays bf16.
//  - xw packed 8 channels per 16B (ushort8): K2 entry load widens to one
//    global_load_dwordx4 and the gather grid HALVES (1448 -> 722 blocks),
//    halving metadata/prologue overhead at identical FMA count.
//  - metadata: packed int4 segments staged once to LDS, rfl -> SGPR.

static __device__ __forceinline__ unsigned short f2bf(float f) {
    unsigned int u = __float_as_uint(f);
    u = (u + 0x7fffu + ((u >> 16) & 1u)) >> 16;
    return (unsigned short)u;
}
static __device__ __forceinline__ unsigned int pack2(float a, float b) {
    return (unsigned int)f2bf(a) | ((unsigned int)f2bf(b) << 16);
}
static __device__ __forceinline__ void bf2_to_f2(unsigned int d, float& lo, float& hi) {
    lo = __uint_as_float(d << 16);
    hi = __uint_as_float(d & 0xffff0000u);
}
static __device__ __forceinline__ int rfl_i(int i) {
    return __builtin_amdgcn_readfirstlane(i);
}
static __device__ __forceinline__ float rfl_f(float f) {
    return __uint_as_float(__builtin_amdgcn_readfirstlane(__float_as_uint(f)));
}
__device__ __forceinline__ void fma4(float4& a, float v, const float4& f) {
    a.x += v * f.x; a.y += v * f.y; a.z += v * f.z; a.w += v * f.w;
}
// 8 bf16 channels -> 8 fp32 FMAs into two float4 accumulators
static __device__ __forceinline__ void fma8(float4& aL, float4& aH, float v, uint4 d) {
    float lo, hi;
    bf2_to_f2(d.x, lo, hi); aL.x += v * lo; aL.y += v * hi;
    bf2_to_f2(d.y, lo, hi); aL.z += v * lo; aL.w += v * hi;
    bf2_to_f2(d.z, lo, hi); aH.x += v * lo; aH.y += v * hi;
    bf2_to_f2(d.w, lo, hi); aH.z += v * lo; aH.w += v * hi;
}

// ---------------------------------------------------------------------------
// K1: blocks [0,768) channel-mix one (k, 256-chunk) into bf16 8ch-packed xw;
// blocks [768, 768+361) build latitude ho's parity-sorted packed segments.
// ---------------------------------------------------------------------------
__global__ __launch_bounds__(256) void mix_bucket_kernel(
    const float* __restrict__ x,      // [CIN][H_IN][W_IN]
    const float* __restrict__ w,      // [COUT][CIN][KSZ]
    const int*   __restrict__ ker_idx,
    const int*   __restrict__ row_idx,
    const int*   __restrict__ col_idx,
    const float* __restrict__ vals,
    uint4* __restrict__ xw8,          // [2][KSZ*H*W] 8 bf16 channels per elem
    int*   __restrict__ gcnt,         // [NLAT][2] padded counts
    int4*  __restrict__ gseg)         // [NLAT][2][MAXB] {base, ps, valbits, 0}
{
    const int tid = threadIdx.x;

    if (blockIdx.x >= NMIX_BLK) {
        // ---- parity-sorted packed bucket build for latitude ho ----
        const int ho = blockIdx.x - NMIX_BLK;
        __shared__ int   s_cnt[2];
        __shared__ int   s_b [2 * MAXB];
        __shared__ int   s_ps[2 * MAXB];
        __shared__ float s_v [2 * MAXB];

        if (tid < 2) s_cnt[tid] = 0;
        if (tid < 2 * MAXB) { s_b[tid] = 0; s_ps[tid] = 0; s_v[tid] = 0.f; }
        __syncthreads();

        const int cbase = ho * NLON;
        const int4* __restrict__ col4 = (const int4*)col_idx;
        for (int n4 = tid; n4 < NNZ / 4; n4 += 256) {
            const int4 c4 = col4[n4];
#pragma unroll
            for (int j = 0; j < 4; ++j) {
                const int c = (j == 0) ? c4.x : (j == 1) ? c4.y : (j == 2) ? c4.z : c4.w;
                const unsigned d = (unsigned)(c - cbase);   // <720 iff lat==ho
                if (d < (unsigned)NLON) {
                    const int n    = 4 * n4 + j;
                    const int pe   = (int)(d & 1u);
                    const int slot = atomicAdd(&s_cnt[pe], 1);
                    if (slot < MAXB) {
                        // base in ushort8 units: (k*H + row)*W
                        s_b [pe * MAXB + slot] = (ker_idx[n] * H_IN + row_idx[n]) * W_IN;
                        s_ps[pe * MAXB + slot] = (int)(d >> 1);
                        s_v [pe * MAXB + slot] = vals[n];
                    }
                }
            }
        }
        __syncthreads();
        if (tid < 2) {
            int c = s_cnt[tid] < MAXB ? s_cnt[tid] : MAXB;
            gcnt[ho * 2 + tid] = (c + 3) & ~3;   // x4-padded; pad slots are zero
        }
        for (int i = tid; i < 2 * MAXB; i += 256)
            gseg[ho * 2 * MAXB + i] =
                make_int4(s_b[i], s_ps[i], __float_as_int(s_v[i]), 0);
        return;
    }

    // ---- channel mix for one (k, chunk): k is block-uniform ----
    const int k   = blockIdx.x >> 8;          // 0..2
    const int pos = (blockIdx.x & 255) * 256 + tid;

    __shared__ float sw[CIN * COUT];          // this k's slice, layout [c][co]
    {
        const int co = tid & 15, c = tid >> 4;
        sw[tid] = w[(co * CIN + c) * KSZ + k];
    }
    __syncthreads();

    if (pos >= HW) return;

    float4 a0 = make_float4(0.f, 0.f, 0.f, 0.f), a1 = a0, a2 = a0, a3 = a0;
#pragma unroll
    for (int c = 0; c < CIN; ++c) {
        const float xv = x[c * HW + pos];
        const float4* wr = (const float4*)(sw + c * COUT);   // broadcast b128
        fma4(a0, xv, wr[0]); fma4(a1, xv, wr[1]);
        fma4(a2, xv, wr[2]); fma4(a3, xv, wr[3]);
    }

    const int e = k * HW + pos;               // elem index within a half-slice
    uint4 u;
    u.x = pack2(a0.x, a0.y); u.y = pack2(a0.z, a0.w);
    u.z = pack2(a1.x, a1.y); u.w = pack2(a1.z, a1.w);
    xw8[0 * KHW + e] = u;                     // channels 0..7
    u.x = pack2(a2.x, a2.y); u.y = pack2(a2.z, a2.w);
    u.z = pack2(a3.x, a3.y); u.w = pack2(a3.z, a3.w);
    xw8[1 * KHW + e] = u;                     // channels 8..15
}

// ---------------------------------------------------------------------------
// K2: gather. grid = 722 (ho, ch-half): h = bid&1 -> mod-8 dispatch keeps
// each 3.1MB half-slice on a 4-XCD subset (L2-fit). Thread t owns lon pair
// (2t, 2t+1), 8 channels. Per entry: one 16B dwordx4 load + 8 FMA; x4 entry
// unroll = 4 loads in flight; metadata int4-staged in LDS, rfl -> SGPR.
// ---------------------------------------------------------------------------
__global__ __launch_bounds__(384) void gather_kernel(
    const uint4* __restrict__ xw8,    // [2][KSZ*H*W] 8 bf16 channels
    const float* __restrict__ bias,   // [COUT]
    const int*   __restrict__ gcnt,
    const int4*  __restrict__ gseg,
    float* __restrict__ out)          // [COUT][NLAT][NLON]
{
    const int bid = blockIdx.x;             // [0, 722)
    const int h   = bid & 1;                // channel half
    const int ho  = bid >> 1;
    const int tid = threadIdx.x;

    __shared__ int4 s_seg[2 * MAXB];
    if (tid < 2 * MAXB) s_seg[tid] = gseg[ho * 2 * MAXB + tid];
    __syncthreads();

    const int2 cnt2 = ((const int2*)gcnt)[ho];
    const int cntE = rfl_i(cnt2.x);
    const int cntO = rfl_i(cnt2.y);

    if (tid >= 360) return;
    const int t = tid;                      // lon pair (2t, 2t+1)

    const float4 bL = ((const float4*)bias)[2 * h];
    const float4 bH = ((const float4*)bias)[2 * h + 1];
    float4 accEL = bL, accEH = bH, accOL = bL, accOH = bH;
    const uint4* __restrict__ slice = xw8 + (size_t)h * KHW;

    // x4-unrolled parity segment: counts are multiples of 4, pads have v=0
#define SEG(PE, CNT, ACCL, ACCH)                                                \
    for (int e = 0; e < (CNT); e += 4) {                                        \
        const int4 s0 = s_seg[(PE) * MAXB + e + 0];                             \
        const int4 s1 = s_seg[(PE) * MAXB + e + 1];                             \
        const int4 s2 = s_seg[(PE) * MAXB + e + 2];                             \
        const int4 s3 = s_seg[(PE) * MAXB + e + 3];                             \
        const int   b0 = rfl_i(s0.x), b1 = rfl_i(s1.x);                         \
        const int   b2 = rfl_i(s2.x), b3 = rfl_i(s3.x);                         \
        const int   p0 = rfl_i(s0.y), p1 = rfl_i(s1.y);                         \
        const int   p2 = rfl_i(s2.y), p3 = rfl_i(s3.y);                         \
        const float v0 = rfl_f(__int_as_float(s0.z));                           \
        const float v1 = rfl_f(__int_as_float(s1.z));                           \
        const float v2 = rfl_f(__int_as_float(s2.z));                           \
        const float v3 = rfl_f(__int_as_float(s3.z));                           \
        int y0 = t - p0; y0 += (y0 >> 31) & 360;                                \
        int y1 = t - p1; y1 += (y1 >> 31) & 360;                                \
        int y2 = t - p2; y2 += (y2 >> 31) & 360;                                \
        int y3 = t - p3; y3 += (y3 >> 31) & 360;                                \
        const uint4 f0 = slice[b0 + y0];                                        \
        const uint4 f1 = slice[b1 + y1];                                        \
        const uint4 f2 = slice[b2 + y2];                                        \
        const uint4 f3 = slice[b3 + y3];                                        \
        fma8(ACCL, ACCH, v0, f0); fma8(ACCL, ACCH, v1, f1);                     \
        fma8(ACCL, ACCH, v2, f2); fma8(ACCL, ACCH, v3, f3);                     \
    }

    SEG(0, cntE, accEL, accEH)
    SEG(1, cntO, accOL, accOH)
#undef SEG

    const float2 rr[8] = {
        make_float2(accEL.x, accOL.x), make_float2(accEL.y, accOL.y),
        make_float2(accEL.z, accOL.z), make_float2(accEL.w, accOL.w),
        make_float2(accEH.x, accOH.x), make_float2(accEH.y, accOH.y),
        make_float2(accEH.z, accOH.z), make_float2(accEH.w, accOH.w) };
#pragma unroll
    for (int j = 0; j < 8; ++j) {
        const int co = 8 * h + j;
        *(float2*)(out + ((size_t)co * NLAT + ho) * NLON + 2 * t) = rr[j];
    }
}

// ---------------------------------------------------------------------------
extern "C" void kernel_launch(void* const* d_in, const int* in_sizes, int n_in,
                              void* d_out, int out_size, void* d_ws, size_t ws_size,
                              hipStream_t stream) {
    const float* x       = (const float*)d_in[0];
    const float* weight  = (const float*)d_in[1];
    const float* bias    = (const float*)d_in[2];
    const int*   ker_idx = (const int*)d_in[3];
    const int*   row_idx = (const int*)d_in[4];
    const int*   col_idx = (const int*)d_in[5];
    const float* vals    = (const float*)d_in[6];
    float* out = (float*)d_out;

    // workspace layout (poison fill is unconditional -> ws use is free)
    uint4* xw8  = (uint4*)d_ws;                             // 6,255,360 B
    int*   gcnt = (int*)((char*)d_ws + XW_BYTES);           // [NLAT*2]
    int4*  gseg = (int4*)((char*)d_ws + XW_BYTES + 4096);   // [NLAT*2*MAXB]

    mix_bucket_kernel<<<NMIX_BLK + NLAT, 256, 0, stream>>>(
        x, weight, ker_idx, row_idx, col_idx, vals, xw8, gcnt, gseg);
    gather_kernel<<<NLAT * 2, 384, 0, stream>>>(xw8, bias, gcnt, gseg, out);
}